// Round 8
// baseline (246.818 us; speedup 1.0000x reference)
//
#include <hip/hip_runtime.h>
#include <hip/hip_bf16.h>
#include <math.h>

#define N_TOK 8192
#define HDIM  1024
#define NE    8
#define TILE  128
#define BK    64
#define NKT   (HDIM / BK)          // 16 K-steps
#define MT_MAX 64                  // 64*128 = 8192 rows capacity per expert (fully general)
#define NT_N  (HDIM / TILE)        // 8 n-tiles
#define GEMM_GRID (NE * NT_N * MT_MAX)   // 4096 blocks, ~1090 active when balanced
#define NGATE (N_TOK / 16)         // 512 gate blocks (16 tokens each, 4/wave)
#define NCONV 2048                 // convert_w blocks (4 float4 / thread)

typedef __attribute__((ext_vector_type(8))) short bf16x8;
typedef __attribute__((ext_vector_type(4))) float f32x4;
typedef unsigned short u16;

__device__ __forceinline__ u16 f2bf(float f) {
    union { float f; unsigned u; } v; v.f = f;
    unsigned r = v.u + 0x7FFFu + ((v.u >> 16) & 1u);   // round-to-nearest-even
    return (u16)(r >> 16);
}

__device__ __forceinline__ void gld_lds16(const void* g, void* lds) {
    __builtin_amdgcn_global_load_lds(
        (const __attribute__((address_space(1))) unsigned int*)g,
        (__attribute__((address_space(3))) unsigned int*)lds,
        16, 0, 0);
}

// ---- prep (round-7 verbatim) ----
// Blocks [0,NGATE): gate + x->bf16, 4 tokens/wave, all 16 x-loads hoisted (MLP).
// Blocks [NGATE,..): expert_w -> bf16, 4 float4/thread. Block NGATE also zeroes
// counts[] (compact reads counts only after prep completes, via stream order).
__global__ __launch_bounds__(256)
void prep_kernel(const float* __restrict__ w, u16* __restrict__ wbf,
                 const float* __restrict__ x,
                 const float* __restrict__ gate_w,
                 const float* __restrict__ gate_b,
                 u16* __restrict__ xbf,
                 int* __restrict__ eids,       // [N_TOK] e0 | e1<<8
                 float2* __restrict__ gatesv,  // [N_TOK] (g0,g1)
                 int* __restrict__ counts)     // [NE] zeroed here
{
    int bid = blockIdx.x;
    if (bid >= NGATE) {
        if (bid == NGATE && threadIdx.x < NE) counts[threadIdx.x] = 0;
        size_t base = (size_t)(bid - NGATE) * 1024 + threadIdx.x;   // float4 index
#pragma unroll
        for (int it = 0; it < 4; ++it) {
            size_t i = base + (size_t)it * 256;
            float4 v = ((const float4*)w)[i];
            ushort4 b;
            b.x = f2bf(v.x); b.y = f2bf(v.y); b.z = f2bf(v.z); b.w = f2bf(v.w);
            ((ushort4*)wbf)[i] = b;
        }
        return;
    }
    int wave = threadIdx.x >> 6, lane = threadIdx.x & 63;
    int tbase = bid * 16 + wave * 4;                 // 4 tokens per wave

    const float4* xt[4];
    ushort4* xb[4];
#pragma unroll
    for (int j = 0; j < 4; ++j) {
        xt[j] = (const float4*)(x + (size_t)(tbase + j) * HDIM);
        xb[j] = (ushort4*)(xbf + (size_t)(tbase + j) * HDIM);
    }

    // hoist all 16 x loads (4 tokens x 4 fragments) -> max MLP
    float4 xv[4][4];   // [i][j]
#pragma unroll
    for (int i = 0; i < 4; ++i)
#pragma unroll
        for (int j = 0; j < 4; ++j)
            xv[i][j] = xt[j][i * 64 + lane];

    // bf16 conversion + store
#pragma unroll
    for (int i = 0; i < 4; ++i)
#pragma unroll
        for (int j = 0; j < 4; ++j) {
            float4 v = xv[i][j];
            ushort4 b;
            b.x = f2bf(v.x); b.y = f2bf(v.y); b.z = f2bf(v.z); b.w = f2bf(v.w);
            xb[j][i * 64 + lane] = b;
        }

    float acc[4][NE];
#pragma unroll
    for (int j = 0; j < 4; ++j)
#pragma unroll
        for (int e = 0; e < NE; ++e) acc[j][e] = 0.f;

#pragma unroll
    for (int i = 0; i < 4; ++i) {
        int f = i * 64 + lane;
        float4 gw[NE];
#pragma unroll
        for (int e = 0; e < NE; ++e)
            gw[e] = ((const float4*)(gate_w + e * HDIM))[f];
#pragma unroll
        for (int j = 0; j < 4; ++j) {
            float4 v = xv[i][j];
#pragma unroll
            for (int e = 0; e < NE; ++e)
                acc[j][e] += v.x * gw[e].x + v.y * gw[e].y + v.z * gw[e].z + v.w * gw[e].w;
        }
    }
#pragma unroll
    for (int j = 0; j < 4; ++j)
#pragma unroll
        for (int e = 0; e < NE; ++e)
            for (int off = 32; off > 0; off >>= 1)
                acc[j][e] += __shfl_down(acc[j][e], off);

    if (lane == 0) {
#pragma unroll
        for (int j = 0; j < 4; ++j) {
            int t = tbase + j;
            float logit[NE];
            float mx = -1e30f;
#pragma unroll
            for (int e = 0; e < NE; ++e) {
                logit[e] = acc[j][e] + gate_b[e];
                mx = fmaxf(mx, logit[e]);
            }
            float p[NE], s = 0.f;
#pragma unroll
            for (int e = 0; e < NE; ++e) { p[e] = expf(logit[e] - mx); s += p[e]; }
            float inv = 1.f / s;
            int i0 = 0;
#pragma unroll
            for (int e = 1; e < NE; ++e) if (logit[e] > logit[i0]) i0 = e;
            int i1 = (i0 == 0) ? 1 : 0;
#pragma unroll
            for (int e = 0; e < NE; ++e) if (e != i0 && logit[e] > logit[i1]) i1 = e;

            eids[t]   = i0 | (i1 << 8);
            gatesv[t] = make_float2(p[i0] * inv, p[i1] * inv);
        }
    }
}

// ---- compact (round-7 verbatim): 32 blocks, LDS sub-histograms + one
// block-range atomic per (block,expert) = 256 global atomics total.
__global__ __launch_bounds__(256)
void compact_kernel(const int* __restrict__ eids,
                    const float2* __restrict__ gatesv,
                    int* __restrict__ tok_list, float* __restrict__ gate_list,
                    int* __restrict__ counts)
{
    __shared__ int lh[16][NE];
    __shared__ int lbase[16][NE];
    int tid = threadIdx.x;
    int t = blockIdx.x * 256 + tid;
    if (tid < 16 * NE) ((int*)lh)[tid] = 0;
    __syncthreads();
    int bucket = tid & 15;

    int ee = eids[t];
    int e0 = ee & 255, e1 = (ee >> 8) & 255;
    float2 gv = gatesv[t];
    int r0 = atomicAdd(&lh[bucket][e0], 1);
    int r1 = atomicAdd(&lh[bucket][e1], 1);
    __syncthreads();

    if (tid < NE) {
        int pre[16];
        int run = 0;
#pragma unroll
        for (int b = 0; b < 16; ++b) { pre[b] = run; run += lh[b][tid]; }
        int base = atomicAdd(&counts[tid], run);    // device-scope block reservation
#pragma unroll
        for (int b = 0; b < 16; ++b) lbase[b][tid] = base + pre[b];
    }
    __syncthreads();

    int p0 = lbase[bucket][e0] + r0;
    tok_list[e0 * N_TOK + p0]  = t * 2;        // token*2 + slot
    gate_list[e0 * N_TOK + p0] = gv.x;
    int p1 = lbase[bucket][e1] + r1;
    tok_list[e1 * N_TOK + p1]  = t * 2 + 1;
    gate_list[e1 * N_TOK + p1] = gv.y;
}

// ---- grouped per-expert GEMM: K-loop BYTE-IDENTICAL to rounds 3/5/7 (64.2us,
// MfmaUtil 21.6%, 0 conflicts, verified 3x). ONLY the epilogue changes:
// plain stores to out/part1  ->  fire-and-forget global_atomic_add_f32 into
// pre-zeroed out. Two adds per element commute bit-exactly ((0+a)+b == (0+b)+a),
// so numerics == combine path. No fences needed (adds are order-free).
// Removes part1 (32MB) + combine kernel (96MB + boundary).
// Round-1's atomic regression was confounded (drain-vmcnt + 1blk/CU 256d tiles);
// this isolates the atomic variable cleanly. Kill-criterion: GEMM > 85us.
__global__ __launch_bounds__(256, 2)
void moe_gemm_kernel(const u16* __restrict__ xbf,
                     const u16* __restrict__ wbf,
                     const float* __restrict__ expert_b,
                     const int* __restrict__ counts,
                     const int* __restrict__ tok_list,
                     const float* __restrict__ gate_list,
                     float* __restrict__ out)      // pre-zeroed, atomic-accumulated
{
    int bid = blockIdx.x;
    int e   = bid & 7;                 // XCD pin
    int n0  = ((bid >> 3) & 7) * TILE;
    int m0  = (bid >> 6) * TILE;
    int cnt = counts[e];
    if (m0 >= cnt) return;

    __shared__ __align__(16) u16 As[2][1024 * 8];   // 2 x 16 KB
    __shared__ __align__(16) u16 Bs[2][1024 * 8];   // 2 x 16 KB  (64 KB total)

    int tid = threadIdx.x;
    int w = tid >> 6, l = tid & 63;

    const u16* aP[4];
    const u16* bP[4];
#pragma unroll
    for (int j = 0; j < 4; ++j) {
        int s = j * 256 + tid;          // slot 0..1023
        int r = s >> 3;                 // row 0..127
        int cs = (s & 7) ^ (r & 7);     // pre-swizzled source chunk
        int tr = m0 + r; if (tr > cnt - 1) tr = cnt - 1;   // dup rows discarded in epilogue
        int lst = tok_list[e * N_TOK + tr];
        aP[j] = xbf + (size_t)(lst >> 1) * HDIM + cs * 8;
        bP[j] = wbf + (size_t)(e * HDIM + n0 + r) * HDIM + cs * 8;
    }

    int wm = (w >> 1) * 64, wn = (w & 1) * 64;   // 2M x 2N wave grid
    int lrow = l & 15, quad = l >> 4;
    int cxbase = lrow & 7;

    f32x4 acc[4][4];
#pragma unroll
    for (int mi = 0; mi < 4; ++mi)
#pragma unroll
        for (int ni = 0; ni < 4; ++ni)
            acc[mi][ni] = (f32x4){0.f, 0.f, 0.f, 0.f};

    auto stage = [&](int b, int k0) {
#pragma unroll
        for (int j = 0; j < 4; ++j) {
            gld_lds16(aP[j] + k0, &As[b][(size_t)(j * 256 + w * 64) * 8]);
            gld_lds16(bP[j] + k0, &Bs[b][(size_t)(j * 256 + w * 64) * 8]);
        }
    };

    // prologue: both buffers in flight (8 loads/thread each)
    stage(0, 0);
    stage(1, BK);

    int buf = 0;
    for (int kt = 0; kt < NKT; ++kt) {
        // this kt's batch (oldest 8 loads) retired; newer 8 stay in flight
        if (kt == NKT - 1) asm volatile("s_waitcnt vmcnt(0)" ::: "memory");
        else               asm volatile("s_waitcnt vmcnt(8)" ::: "memory");
        __builtin_amdgcn_s_barrier();

        const u16* Ab = As[buf];
        const u16* Bb = Bs[buf];
#pragma unroll
        for (int kk = 0; kk < 2; ++kk) {
            int cx = (kk * 4 + quad) ^ cxbase;              // swizzled chunk for this lane
            bf16x8 af[4], bfr[4];
#pragma unroll
            for (int i = 0; i < 4; ++i) {
                int ra = wm + i * 16 + lrow;
                int rb = wn + i * 16 + lrow;
                af[i]  = *(const bf16x8*)(Ab + (size_t)(ra * 8 + cx) * 8);
                bfr[i] = *(const bf16x8*)(Bb + (size_t)(rb * 8 + cx) * 8);
            }
#pragma unroll
            for (int mi = 0; mi < 4; ++mi)
#pragma unroll
                for (int ni = 0; ni < 4; ++ni)
                    acc[mi][ni] = __builtin_amdgcn_mfma_f32_16x16x32_bf16(
                        af[mi], bfr[ni], acc[mi][ni], 0, 0, 0);
        }

        asm volatile("s_waitcnt lgkmcnt(0)" ::: "memory");  // my ds_reads done
        __builtin_amdgcn_s_barrier();                       // everyone's reads done
        if (kt + 2 < NKT) stage(buf, (kt + 2) * BK);        // refill freed buffer
        buf ^= 1;
    }

    // epilogue: bias + gate, atomic-add both slots into pre-zeroed out
#pragma unroll
    for (int mi = 0; mi < 4; ++mi) {
#pragma unroll
        for (int rr = 0; rr < 4; ++rr) {
            int listRow = m0 + wm + mi * 16 + quad * 4 + rr;
            if (listRow < cnt) {
                int   lst = tok_list[e * N_TOK + listRow];
                float g   = gate_list[e * N_TOK + listRow];
                float* dst = out + (size_t)(lst >> 1) * HDIM;
#pragma unroll
                for (int ni = 0; ni < 4; ++ni) {
                    int col = n0 + wn + ni * 16 + lrow;
                    atomicAdd(&dst[col], (acc[mi][ni][rr] + expert_b[e * HDIM + col]) * g);
                }
            }
        }
    }
}

extern "C" void kernel_launch(void* const* d_in, const int* in_sizes, int n_in,
                              void* d_out, int out_size, void* d_ws, size_t ws_size,
                              hipStream_t stream)
{
    const float* x        = (const float*)d_in[0];
    const float* gate_w   = (const float*)d_in[1];
    const float* gate_b   = (const float*)d_in[2];
    const float* expert_w = (const float*)d_in[3];
    const float* expert_b = (const float*)d_in[4];
    float* out = (float*)d_out;

    char* ws = (char*)d_ws;
    int*    eids      = (int*)(ws);                         // 32 KB
    float2* gatesv    = (float2*)(ws + (64 << 10));         // 64 KB
    int*    counts    = (int*)(ws + (132 << 10));           // 32 B
    int*    tok_list  = (int*)(ws + (136 << 10));           // 256 KB
    float*  gate_list = (float*)(ws + (136 << 10) + NE * N_TOK * 4); // 256 KB
    u16*    xbf       = (u16*)(ws + (1 << 20));             // 16 MB
    u16*    wbf       = xbf + (size_t)N_TOK * HDIM;         // 16 MB

    hipMemsetAsync(out, 0, (size_t)N_TOK * HDIM * sizeof(float), stream);

    prep_kernel<<<NCONV + NGATE, 256, 0, stream>>>(expert_w, wbf, x, gate_w, gate_b,
                                                   xbf, eids, gatesv, counts);
    compact_kernel<<<N_TOK / 256, 256, 0, stream>>>(eids, gatesv, tok_list, gate_list, counts);

    moe_gemm_kernel<<<GEMM_GRID, 256, 0, stream>>>(xbf, wbf, expert_b,
                                                   counts, tok_list, gate_list, out);
}

// Round 9
// 193.027 us; speedup vs baseline: 1.2787x; 1.2787x over previous
//
#include <hip/hip_runtime.h>
#include <hip/hip_bf16.h>
#include <math.h>

#define N_TOK 8192
#define HDIM  1024
#define NE    8
#define TILE  128
#define BK    64
#define NKT   (HDIM / BK)          // 16 K-steps
#define MT_MAX 64                  // 64*128 = 8192 rows capacity per expert (fully general)
#define NT_N  (HDIM / TILE)        // 8 n-tiles
#define GEMM_GRID (NE * NT_N * MT_MAX)   // 4096 blocks, ~1090 active when balanced
#define NGATE (N_TOK / 16)         // 512 gate blocks (16 tokens each, 4/wave)
#define NCONV 1024                 // convert_w blocks (8 float4 / thread)

typedef __attribute__((ext_vector_type(8))) short bf16x8;
typedef __attribute__((ext_vector_type(4))) float f32x4;
typedef unsigned short u16;

__device__ __forceinline__ u16 f2bf(float f) {
    union { float f; unsigned u; } v; v.f = f;
    unsigned r = v.u + 0x7FFFu + ((v.u >> 16) & 1u);   // round-to-nearest-even
    return (u16)(r >> 16);
}

__device__ __forceinline__ void gld_lds16(const void* g, void* lds) {
    __builtin_amdgcn_global_load_lds(
        (const __attribute__((address_space(1))) unsigned int*)g,
        (__attribute__((address_space(3))) unsigned int*)lds,
        16, 0, 0);
}

// ---- prep ----
// Round-8 accounting isolated prep at ~85-90us vs a ~16us BW roofline, with
// round-4 counters showing latency-bound (VALU 4.5%, HBM 2%, occ 41%). The
// dependent-miss chain is the 32 gate_w L2 loads per gate wave. Fix: stage
// gate_w (32KB) into LDS once per block (global_load_lds, linear dest), then
// the inner loop reads LDS (~120cyc, conflict-free float4 pattern).
// Conv blocks: 8 float4/thread (8 independent loads in flight).
// Block NGATE zeroes counts[] (stream order protects compact's read).
__global__ __launch_bounds__(256)
void prep_kernel(const float* __restrict__ w, u16* __restrict__ wbf,
                 const float* __restrict__ x,
                 const float* __restrict__ gate_w,
                 const float* __restrict__ gate_b,
                 u16* __restrict__ xbf,
                 int* __restrict__ eids,       // [N_TOK] e0 | e1<<8
                 float2* __restrict__ gatesv,  // [N_TOK] (g0,g1)
                 int* __restrict__ counts)     // [NE] zeroed here
{
    __shared__ __align__(16) float gwLDS[NE * HDIM];   // 32 KB

    int bid = blockIdx.x;
    if (bid >= NGATE) {
        if (bid == NGATE && threadIdx.x < NE) counts[threadIdx.x] = 0;
        size_t base = (size_t)(bid - NGATE) * 2048 + threadIdx.x;   // float4 index
#pragma unroll
        for (int it = 0; it < 8; ++it) {
            size_t i = base + (size_t)it * 256;
            float4 v = ((const float4*)w)[i];
            ushort4 b;
            b.x = f2bf(v.x); b.y = f2bf(v.y); b.z = f2bf(v.z); b.w = f2bf(v.w);
            ((ushort4*)wbf)[i] = b;
        }
        return;
    }

    // stage gate_w -> LDS (2048 float4s, 8 per thread, linear async copy)
#pragma unroll
    for (int it = 0; it < 8; ++it) {
        int idx = it * 256 + threadIdx.x;                  // float4 slot
        gld_lds16((const float*)gate_w + (size_t)idx * 4, gwLDS + (size_t)idx * 4);
    }

    int wave = threadIdx.x >> 6, lane = threadIdx.x & 63;
    int tbase = bid * 16 + wave * 4;                 // 4 tokens per wave

    const float4* xt[4];
    ushort4* xb[4];
#pragma unroll
    for (int j = 0; j < 4; ++j) {
        xt[j] = (const float4*)(x + (size_t)(tbase + j) * HDIM);
        xb[j] = (ushort4*)(xbf + (size_t)(tbase + j) * HDIM);
    }

    // hoist all 16 x loads (4 tokens x 4 fragments) -> max MLP, overlaps staging
    float4 xv[4][4];   // [i][j]
#pragma unroll
    for (int i = 0; i < 4; ++i)
#pragma unroll
        for (int j = 0; j < 4; ++j)
            xv[i][j] = xt[j][i * 64 + lane];

    // bf16 conversion + store
#pragma unroll
    for (int i = 0; i < 4; ++i)
#pragma unroll
        for (int j = 0; j < 4; ++j) {
            float4 v = xv[i][j];
            ushort4 b;
            b.x = f2bf(v.x); b.y = f2bf(v.y); b.z = f2bf(v.z); b.w = f2bf(v.w);
            xb[j][i * 64 + lane] = b;
        }

    __syncthreads();   // gate_w staged (drains vmcnt + lgkm before barrier)

    float acc[4][NE];
#pragma unroll
    for (int j = 0; j < 4; ++j)
#pragma unroll
        for (int e = 0; e < NE; ++e) acc[j][e] = 0.f;

#pragma unroll
    for (int i = 0; i < 4; ++i) {
        int f = i * 64 + lane;
        float4 gw[NE];
#pragma unroll
        for (int e = 0; e < NE; ++e)
            gw[e] = ((const float4*)(gwLDS + e * HDIM))[f];
#pragma unroll
        for (int j = 0; j < 4; ++j) {
            float4 v = xv[i][j];
#pragma unroll
            for (int e = 0; e < NE; ++e)
                acc[j][e] += v.x * gw[e].x + v.y * gw[e].y + v.z * gw[e].z + v.w * gw[e].w;
        }
    }
#pragma unroll
    for (int j = 0; j < 4; ++j)
#pragma unroll
        for (int e = 0; e < NE; ++e)
            for (int off = 32; off > 0; off >>= 1)
                acc[j][e] += __shfl_down(acc[j][e], off);

    if (lane == 0) {
#pragma unroll
        for (int j = 0; j < 4; ++j) {
            int t = tbase + j;
            float logit[NE];
            float mx = -1e30f;
#pragma unroll
            for (int e = 0; e < NE; ++e) {
                logit[e] = acc[j][e] + gate_b[e];
                mx = fmaxf(mx, logit[e]);
            }
            float p[NE], s = 0.f;
#pragma unroll
            for (int e = 0; e < NE; ++e) { p[e] = expf(logit[e] - mx); s += p[e]; }
            float inv = 1.f / s;
            int i0 = 0;
#pragma unroll
            for (int e = 1; e < NE; ++e) if (logit[e] > logit[i0]) i0 = e;
            int i1 = (i0 == 0) ? 1 : 0;
#pragma unroll
            for (int e = 0; e < NE; ++e) if (e != i0 && logit[e] > logit[i1]) i1 = e;

            eids[t]   = i0 | (i1 << 8);
            gatesv[t] = make_float2(p[i0] * inv, p[i1] * inv);
        }
    }
}

// ---- compact (round-7 verbatim): 32 blocks, LDS sub-histograms + one
// block-range atomic per (block,expert) = 256 global atomics total.
__global__ __launch_bounds__(256)
void compact_kernel(const int* __restrict__ eids,
                    const float2* __restrict__ gatesv,
                    int* __restrict__ tok_list, float* __restrict__ gate_list,
                    int* __restrict__ counts)
{
    __shared__ int lh[16][NE];
    __shared__ int lbase[16][NE];
    int tid = threadIdx.x;
    int t = blockIdx.x * 256 + tid;
    if (tid < 16 * NE) ((int*)lh)[tid] = 0;
    __syncthreads();
    int bucket = tid & 15;

    int ee = eids[t];
    int e0 = ee & 255, e1 = (ee >> 8) & 255;
    float2 gv = gatesv[t];
    int r0 = atomicAdd(&lh[bucket][e0], 1);
    int r1 = atomicAdd(&lh[bucket][e1], 1);
    __syncthreads();

    if (tid < NE) {
        int pre[16];
        int run = 0;
#pragma unroll
        for (int b = 0; b < 16; ++b) { pre[b] = run; run += lh[b][tid]; }
        int base = atomicAdd(&counts[tid], run);    // device-scope block reservation
#pragma unroll
        for (int b = 0; b < 16; ++b) lbase[b][tid] = base + pre[b];
    }
    __syncthreads();

    int p0 = lbase[bucket][e0] + r0;
    tok_list[e0 * N_TOK + p0]  = t * 2;        // token*2 + slot
    gate_list[e0 * N_TOK + p0] = gv.x;
    int p1 = lbase[bucket][e1] + r1;
    tok_list[e1 * N_TOK + p1]  = t * 2 + 1;
    gate_list[e1 * N_TOK + p1] = gv.y;
}

// ---- grouped per-expert GEMM (rounds 3/5/7 VERBATIM: 64.2us, MfmaUtil 21.6%,
// 0 conflicts, verified 3x). Counted-vmcnt double-buffer (vmcnt(8), never 0 in
// main loop -- round-6 drain variant 70.5us REFUTED; round-8 atomic epilogue
// 131us REFUTED: 16.8M f32 atomics cost ~67us). Plain stores + combine.
// Mapping: bid = (m*8+n)*8 + e => XCD(bid%8)==expert e (FETCH 81->37MB win).
__global__ __launch_bounds__(256, 2)
void moe_gemm_kernel(const u16* __restrict__ xbf,
                     const u16* __restrict__ wbf,
                     const float* __restrict__ expert_b,
                     const int* __restrict__ counts,
                     const int* __restrict__ tok_list,
                     const float* __restrict__ gate_list,
                     float* __restrict__ out,      // slot0 partials
                     float* __restrict__ part1)    // slot1 partials
{
    int bid = blockIdx.x;
    int e   = bid & 7;                 // XCD pin
    int n0  = ((bid >> 3) & 7) * TILE;
    int m0  = (bid >> 6) * TILE;
    int cnt = counts[e];
    if (m0 >= cnt) return;

    __shared__ __align__(16) u16 As[2][1024 * 8];   // 2 x 16 KB
    __shared__ __align__(16) u16 Bs[2][1024 * 8];   // 2 x 16 KB  (64 KB total)

    int tid = threadIdx.x;
    int w = tid >> 6, l = tid & 63;

    const u16* aP[4];
    const u16* bP[4];
#pragma unroll
    for (int j = 0; j < 4; ++j) {
        int s = j * 256 + tid;          // slot 0..1023
        int r = s >> 3;                 // row 0..127
        int cs = (s & 7) ^ (r & 7);     // pre-swizzled source chunk
        int tr = m0 + r; if (tr > cnt - 1) tr = cnt - 1;   // dup rows discarded in epilogue
        int lst = tok_list[e * N_TOK + tr];
        aP[j] = xbf + (size_t)(lst >> 1) * HDIM + cs * 8;
        bP[j] = wbf + (size_t)(e * HDIM + n0 + r) * HDIM + cs * 8;
    }

    int wm = (w >> 1) * 64, wn = (w & 1) * 64;   // 2M x 2N wave grid
    int lrow = l & 15, quad = l >> 4;
    int cxbase = lrow & 7;

    f32x4 acc[4][4];
#pragma unroll
    for (int mi = 0; mi < 4; ++mi)
#pragma unroll
        for (int ni = 0; ni < 4; ++ni)
            acc[mi][ni] = (f32x4){0.f, 0.f, 0.f, 0.f};

    auto stage = [&](int b, int k0) {
#pragma unroll
        for (int j = 0; j < 4; ++j) {
            gld_lds16(aP[j] + k0, &As[b][(size_t)(j * 256 + w * 64) * 8]);
            gld_lds16(bP[j] + k0, &Bs[b][(size_t)(j * 256 + w * 64) * 8]);
        }
    };

    // prologue: both buffers in flight (8 loads/thread each)
    stage(0, 0);
    stage(1, BK);

    int buf = 0;
    for (int kt = 0; kt < NKT; ++kt) {
        // this kt's batch (oldest 8 loads) retired; newer 8 stay in flight
        if (kt == NKT - 1) asm volatile("s_waitcnt vmcnt(0)" ::: "memory");
        else               asm volatile("s_waitcnt vmcnt(8)" ::: "memory");
        __builtin_amdgcn_s_barrier();

        const u16* Ab = As[buf];
        const u16* Bb = Bs[buf];
#pragma unroll
        for (int kk = 0; kk < 2; ++kk) {
            int cx = (kk * 4 + quad) ^ cxbase;              // swizzled chunk for this lane
            bf16x8 af[4], bfr[4];
#pragma unroll
            for (int i = 0; i < 4; ++i) {
                int ra = wm + i * 16 + lrow;
                int rb = wn + i * 16 + lrow;
                af[i]  = *(const bf16x8*)(Ab + (size_t)(ra * 8 + cx) * 8);
                bfr[i] = *(const bf16x8*)(Bb + (size_t)(rb * 8 + cx) * 8);
            }
#pragma unroll
            for (int mi = 0; mi < 4; ++mi)
#pragma unroll
                for (int ni = 0; ni < 4; ++ni)
                    acc[mi][ni] = __builtin_amdgcn_mfma_f32_16x16x32_bf16(
                        af[mi], bfr[ni], acc[mi][ni], 0, 0, 0);
        }

        asm volatile("s_waitcnt lgkmcnt(0)" ::: "memory");  // my ds_reads done
        __builtin_amdgcn_s_barrier();                       // everyone's reads done
        if (kt + 2 < NKT) stage(buf, (kt + 2) * BK);        // refill freed buffer
        buf ^= 1;
    }

    // epilogue: bias + gate, plain stores to (token,slot) partial rows
#pragma unroll
    for (int mi = 0; mi < 4; ++mi) {
#pragma unroll
        for (int rr = 0; rr < 4; ++rr) {
            int listRow = m0 + wm + mi * 16 + quad * 4 + rr;
            if (listRow < cnt) {
                int   lst = tok_list[e * N_TOK + listRow];
                float g   = gate_list[e * N_TOK + listRow];
                float* dst = ((lst & 1) ? part1 : out) + (size_t)(lst >> 1) * HDIM;
#pragma unroll
                for (int ni = 0; ni < 4; ++ni) {
                    int col = n0 + wn + ni * 16 + lrow;
                    dst[col] = (acc[mi][ni][rr] + expert_b[e * HDIM + col]) * g;
                }
            }
        }
    }
}

// ---- combine: out += part1, 4 float4/thread (ILP for streaming) ----
__global__ __launch_bounds__(256)
void combine_kernel(float* __restrict__ out, const float* __restrict__ part1) {
    size_t base = (size_t)blockIdx.x * 1024 + threadIdx.x;
    float4 a[4], b[4];
#pragma unroll
    for (int it = 0; it < 4; ++it) {
        size_t i = base + (size_t)it * 256;
        a[it] = ((const float4*)out)[i];
        b[it] = ((const float4*)part1)[i];
    }
#pragma unroll
    for (int it = 0; it < 4; ++it) {
        size_t i = base + (size_t)it * 256;
        a[it].x += b[it].x; a[it].y += b[it].y;
        a[it].z += b[it].z; a[it].w += b[it].w;
        ((float4*)out)[i] = a[it];
    }
}

extern "C" void kernel_launch(void* const* d_in, const int* in_sizes, int n_in,
                              void* d_out, int out_size, void* d_ws, size_t ws_size,
                              hipStream_t stream)
{
    const float* x        = (const float*)d_in[0];
    const float* gate_w   = (const float*)d_in[1];
    const float* gate_b   = (const float*)d_in[2];
    const float* expert_w = (const float*)d_in[3];
    const float* expert_b = (const float*)d_in[4];
    float* out = (float*)d_out;

    char* ws = (char*)d_ws;
    int*    eids      = (int*)(ws);                         // 32 KB
    float2* gatesv    = (float2*)(ws + (64 << 10));         // 64 KB
    int*    counts    = (int*)(ws + (132 << 10));           // 32 B
    int*    tok_list  = (int*)(ws + (136 << 10));           // 256 KB
    float*  gate_list = (float*)(ws + (136 << 10) + NE * N_TOK * 4); // 256 KB
    u16*    xbf       = (u16*)(ws + (1 << 20));             // 16 MB
    u16*    wbf       = xbf + (size_t)N_TOK * HDIM;         // 16 MB
    float*  part1     = (float*)(ws + (33u << 20));         // 32 MB

    prep_kernel<<<NCONV + NGATE, 256, 0, stream>>>(expert_w, wbf, x, gate_w, gate_b,
                                                   xbf, eids, gatesv, counts);
    compact_kernel<<<N_TOK / 256, 256, 0, stream>>>(eids, gatesv, tok_list, gate_list, counts);

    moe_gemm_kernel<<<GEMM_GRID, 256, 0, stream>>>(xbf, wbf, expert_b,
                                                   counts, tok_list, gate_list, out, part1);

    combine_kernel<<<N_TOK * HDIM / 16 / 256, 256, 0, stream>>>(out, part1);
}

// Round 10
// 186.539 us; speedup vs baseline: 1.3231x; 1.0348x over previous
//
#include <hip/hip_runtime.h>
#include <hip/hip_bf16.h>
#include <math.h>

#define N_TOK 8192
#define HDIM  1024
#define NE    8
#define TILE  128
#define BK    64
#define NKT   (HDIM / BK)          // 16 K-steps
#define MT_MAX 64                  // 64*128 = 8192 rows capacity per expert (fully general)
#define NT_N  (HDIM / TILE)        // 8 n-tiles
#define GEMM_GRID (NE * NT_N * MT_MAX)   // 4096 blocks, ~1090 active when balanced
#define NGATE (N_TOK / 16)         // 512 gate blocks (16 tokens each, 4/wave)
#define NCONV 1024                 // convert_w blocks (8 float4 / thread)

typedef __attribute__((ext_vector_type(8))) short bf16x8;
typedef __attribute__((ext_vector_type(4))) float f32x4;
typedef unsigned short u16;

__device__ __forceinline__ u16 f2bf(float f) {
    union { float f; unsigned u; } v; v.f = f;
    unsigned r = v.u + 0x7FFFu + ((v.u >> 16) & 1u);   // round-to-nearest-even
    return (u16)(r >> 16);
}

__device__ __forceinline__ void gld_lds16(const void* g, void* lds) {
    __builtin_amdgcn_global_load_lds(
        (const __attribute__((address_space(1))) unsigned int*)g,
        (__attribute__((address_space(3))) unsigned int*)lds,
        16, 0, 0);
}

// ---- prep (round-9 verbatim: gate_w LDS-staged, 4 tok/wave, conv 8xf4) ----
__global__ __launch_bounds__(256)
void prep_kernel(const float* __restrict__ w, u16* __restrict__ wbf,
                 const float* __restrict__ x,
                 const float* __restrict__ gate_w,
                 const float* __restrict__ gate_b,
                 u16* __restrict__ xbf,
                 int* __restrict__ eids,       // [N_TOK] e0 | e1<<8
                 float2* __restrict__ gatesv,  // [N_TOK] (g0,g1)
                 int* __restrict__ counts)     // [NE] zeroed here
{
    __shared__ __align__(16) float gwLDS[NE * HDIM];   // 32 KB

    int bid = blockIdx.x;
    if (bid >= NGATE) {
        if (bid == NGATE && threadIdx.x < NE) counts[threadIdx.x] = 0;
        size_t base = (size_t)(bid - NGATE) * 2048 + threadIdx.x;   // float4 index
#pragma unroll
        for (int it = 0; it < 8; ++it) {
            size_t i = base + (size_t)it * 256;
            float4 v = ((const float4*)w)[i];
            ushort4 b;
            b.x = f2bf(v.x); b.y = f2bf(v.y); b.z = f2bf(v.z); b.w = f2bf(v.w);
            ((ushort4*)wbf)[i] = b;
        }
        return;
    }

    // stage gate_w -> LDS (2048 float4s, 8 per thread, linear async copy)
#pragma unroll
    for (int it = 0; it < 8; ++it) {
        int idx = it * 256 + threadIdx.x;                  // float4 slot
        gld_lds16((const float*)gate_w + (size_t)idx * 4, gwLDS + (size_t)idx * 4);
    }

    int wave = threadIdx.x >> 6, lane = threadIdx.x & 63;
    int tbase = bid * 16 + wave * 4;                 // 4 tokens per wave

    const float4* xt[4];
    ushort4* xb[4];
#pragma unroll
    for (int j = 0; j < 4; ++j) {
        xt[j] = (const float4*)(x + (size_t)(tbase + j) * HDIM);
        xb[j] = (ushort4*)(xbf + (size_t)(tbase + j) * HDIM);
    }

    float4 xv[4][4];   // [i][j] all 16 x loads hoisted
#pragma unroll
    for (int i = 0; i < 4; ++i)
#pragma unroll
        for (int j = 0; j < 4; ++j)
            xv[i][j] = xt[j][i * 64 + lane];

#pragma unroll
    for (int i = 0; i < 4; ++i)
#pragma unroll
        for (int j = 0; j < 4; ++j) {
            float4 v = xv[i][j];
            ushort4 b;
            b.x = f2bf(v.x); b.y = f2bf(v.y); b.z = f2bf(v.z); b.w = f2bf(v.w);
            xb[j][i * 64 + lane] = b;
        }

    __syncthreads();   // gate_w staged

    float acc[4][NE];
#pragma unroll
    for (int j = 0; j < 4; ++j)
#pragma unroll
        for (int e = 0; e < NE; ++e) acc[j][e] = 0.f;

#pragma unroll
    for (int i = 0; i < 4; ++i) {
        int f = i * 64 + lane;
        float4 gw[NE];
#pragma unroll
        for (int e = 0; e < NE; ++e)
            gw[e] = ((const float4*)(gwLDS + e * HDIM))[f];
#pragma unroll
        for (int j = 0; j < 4; ++j) {
            float4 v = xv[i][j];
#pragma unroll
            for (int e = 0; e < NE; ++e)
                acc[j][e] += v.x * gw[e].x + v.y * gw[e].y + v.z * gw[e].z + v.w * gw[e].w;
        }
    }
#pragma unroll
    for (int j = 0; j < 4; ++j)
#pragma unroll
        for (int e = 0; e < NE; ++e)
            for (int off = 32; off > 0; off >>= 1)
                acc[j][e] += __shfl_down(acc[j][e], off);

    if (lane == 0) {
#pragma unroll
        for (int j = 0; j < 4; ++j) {
            int t = tbase + j;
            float logit[NE];
            float mx = -1e30f;
#pragma unroll
            for (int e = 0; e < NE; ++e) {
                logit[e] = acc[j][e] + gate_b[e];
                mx = fmaxf(mx, logit[e]);
            }
            float p[NE], s = 0.f;
#pragma unroll
            for (int e = 0; e < NE; ++e) { p[e] = expf(logit[e] - mx); s += p[e]; }
            float inv = 1.f / s;
            int i0 = 0;
#pragma unroll
            for (int e = 1; e < NE; ++e) if (logit[e] > logit[i0]) i0 = e;
            int i1 = (i0 == 0) ? 1 : 0;
#pragma unroll
            for (int e = 0; e < NE; ++e) if (e != i0 && logit[e] > logit[i1]) i1 = e;

            eids[t]   = i0 | (i1 << 8);
            gatesv[t] = make_float2(p[i0] * inv, p[i1] * inv);
        }
    }
}

// ---- compact (round-7 verbatim): 32 blocks, LDS sub-histograms + one
// block-range atomic per (block,expert) = 256 global atomics total.
__global__ __launch_bounds__(256)
void compact_kernel(const int* __restrict__ eids,
                    const float2* __restrict__ gatesv,
                    int* __restrict__ tok_list, float* __restrict__ gate_list,
                    int* __restrict__ counts)
{
    __shared__ int lh[16][NE];
    __shared__ int lbase[16][NE];
    int tid = threadIdx.x;
    int t = blockIdx.x * 256 + tid;
    if (tid < 16 * NE) ((int*)lh)[tid] = 0;
    __syncthreads();
    int bucket = tid & 15;

    int ee = eids[t];
    int e0 = ee & 255, e1 = (ee >> 8) & 255;
    float2 gv = gatesv[t];
    int r0 = atomicAdd(&lh[bucket][e0], 1);
    int r1 = atomicAdd(&lh[bucket][e1], 1);
    __syncthreads();

    if (tid < NE) {
        int pre[16];
        int run = 0;
#pragma unroll
        for (int b = 0; b < 16; ++b) { pre[b] = run; run += lh[b][tid]; }
        int base = atomicAdd(&counts[tid], run);    // device-scope block reservation
#pragma unroll
        for (int b = 0; b < 16; ++b) lbase[b][tid] = base + pre[b];
    }
    __syncthreads();

    int p0 = lbase[bucket][e0] + r0;
    tok_list[e0 * N_TOK + p0]  = t * 2;        // token*2 + slot
    gate_list[e0 * N_TOK + p0] = gv.x;
    int p1 = lbase[bucket][e1] + r1;
    tok_list[e1 * N_TOK + p1]  = t * 2 + 1;
    gate_list[e1 * N_TOK + p1] = gv.y;
}

// ---- grouped per-expert GEMM: 128x128 tile, BK=64, counted-vmcnt dbuf, 8 WAVES.
// Round-9 counters: MfmaUtil 21.6 + VALUBusy 17.7 (60% no-issue), DS ~34% busy,
// HBM 26% -> convoy/latency-bound with 1 wave/block/SIMD. Fix: 512 threads,
// wave-tile 64x32 (2M x 4N grid), same LDS (64KB, 2 blocks/CU) -> 4 waves/SIMD.
// DS reads +50% (96 vs 64 b128/block-step) on a 34%-busy pipe -- acceptable.
// Sync skeleton IDENTICAL to the 3x-verified loop, counts rescaled:
// stage = 4 gld_lds16/thread; prologue 8 in flight; vmcnt(4) in main loop
// (never 0); lgkm(0)+barrier then refill. Swizzle math byte-identical.
// Mapping: bid = (m*8+n)*8 + e => XCD(bid%8)==expert e (FETCH 81->37MB win).
__global__ __launch_bounds__(512, 4)
void moe_gemm_kernel(const u16* __restrict__ xbf,
                     const u16* __restrict__ wbf,
                     const float* __restrict__ expert_b,
                     const int* __restrict__ counts,
                     const int* __restrict__ tok_list,
                     const float* __restrict__ gate_list,
                     float* __restrict__ out,      // slot0 partials
                     float* __restrict__ part1)    // slot1 partials
{
    int bid = blockIdx.x;
    int e   = bid & 7;                 // XCD pin
    int n0  = ((bid >> 3) & 7) * TILE;
    int m0  = (bid >> 6) * TILE;
    int cnt = counts[e];
    if (m0 >= cnt) return;

    __shared__ __align__(16) u16 As[2][1024 * 8];   // 2 x 16 KB
    __shared__ __align__(16) u16 Bs[2][1024 * 8];   // 2 x 16 KB  (64 KB total)

    int tid = threadIdx.x;
    int w = tid >> 6, l = tid & 63;

    const u16* aP[2];
    const u16* bP[2];
#pragma unroll
    for (int j = 0; j < 2; ++j) {
        int s = j * 512 + tid;          // slot 0..1023
        int r = s >> 3;                 // row 0..127
        int cs = (s & 7) ^ (r & 7);     // pre-swizzled source chunk
        int tr = m0 + r; if (tr > cnt - 1) tr = cnt - 1;   // dup rows discarded in epilogue
        int lst = tok_list[e * N_TOK + tr];
        aP[j] = xbf + (size_t)(lst >> 1) * HDIM + cs * 8;
        bP[j] = wbf + (size_t)(e * HDIM + n0 + r) * HDIM + cs * 8;
    }

    int wm = (w >> 2) * 64, wn = (w & 3) * 32;   // 2M x 4N wave grid, 64x32/wave
    int lrow = l & 15, quad = l >> 4;
    int cxbase = lrow & 7;

    f32x4 acc[4][2];
#pragma unroll
    for (int mi = 0; mi < 4; ++mi)
#pragma unroll
        for (int ni = 0; ni < 2; ++ni)
            acc[mi][ni] = (f32x4){0.f, 0.f, 0.f, 0.f};

    auto stage = [&](int b, int k0) {
#pragma unroll
        for (int j = 0; j < 2; ++j) {
            gld_lds16(aP[j] + k0, &As[b][(size_t)(j * 512 + w * 64) * 8]);
            gld_lds16(bP[j] + k0, &Bs[b][(size_t)(j * 512 + w * 64) * 8]);
        }
    };

    // prologue: both buffers in flight (4 loads/thread each)
    stage(0, 0);
    stage(1, BK);

    int buf = 0;
    for (int kt = 0; kt < NKT; ++kt) {
        // this kt's batch (oldest 4 loads) retired; newer 4 stay in flight
        if (kt == NKT - 1) asm volatile("s_waitcnt vmcnt(0)" ::: "memory");
        else               asm volatile("s_waitcnt vmcnt(4)" ::: "memory");
        __builtin_amdgcn_s_barrier();

        const u16* Ab = As[buf];
        const u16* Bb = Bs[buf];
#pragma unroll
        for (int kk = 0; kk < 2; ++kk) {
            int cx = (kk * 4 + quad) ^ cxbase;              // swizzled chunk for this lane
            bf16x8 af[4], bfr[2];
#pragma unroll
            for (int i = 0; i < 4; ++i) {
                int ra = wm + i * 16 + lrow;
                af[i] = *(const bf16x8*)(Ab + (size_t)(ra * 8 + cx) * 8);
            }
#pragma unroll
            for (int i = 0; i < 2; ++i) {
                int rb = wn + i * 16 + lrow;
                bfr[i] = *(const bf16x8*)(Bb + (size_t)(rb * 8 + cx) * 8);
            }
#pragma unroll
            for (int mi = 0; mi < 4; ++mi)
#pragma unroll
                for (int ni = 0; ni < 2; ++ni)
                    acc[mi][ni] = __builtin_amdgcn_mfma_f32_16x16x32_bf16(
                        af[mi], bfr[ni], acc[mi][ni], 0, 0, 0);
        }

        asm volatile("s_waitcnt lgkmcnt(0)" ::: "memory");  // my ds_reads done
        __builtin_amdgcn_s_barrier();                       // everyone's reads done
        if (kt + 2 < NKT) stage(buf, (kt + 2) * BK);        // refill freed buffer
        buf ^= 1;
    }

    // epilogue: bias + gate, plain stores to (token,slot) partial rows
#pragma unroll
    for (int mi = 0; mi < 4; ++mi) {
#pragma unroll
        for (int rr = 0; rr < 4; ++rr) {
            int listRow = m0 + wm + mi * 16 + quad * 4 + rr;
            if (listRow < cnt) {
                int   lst = tok_list[e * N_TOK + listRow];
                float g   = gate_list[e * N_TOK + listRow];
                float* dst = ((lst & 1) ? part1 : out) + (size_t)(lst >> 1) * HDIM;
#pragma unroll
                for (int ni = 0; ni < 2; ++ni) {
                    int col = n0 + wn + ni * 16 + lrow;
                    dst[col] = (acc[mi][ni][rr] + expert_b[e * HDIM + col]) * g;
                }
            }
        }
    }
}

// ---- combine: out += part1, 4 float4/thread (ILP for streaming) ----
__global__ __launch_bounds__(256)
void combine_kernel(float* __restrict__ out, const float* __restrict__ part1) {
    size_t base = (size_t)blockIdx.x * 1024 + threadIdx.x;
    float4 a[4], b[4];
#pragma unroll
    for (int it = 0; it < 4; ++it) {
        size_t i = base + (size_t)it * 256;
        a[it] = ((const float4*)out)[i];
        b[it] = ((const float4*)part1)[i];
    }
#pragma unroll
    for (int it = 0; it < 4; ++it) {
        size_t i = base + (size_t)it * 256;
        a[it].x += b[it].x; a[it].y += b[it].y;
        a[it].z += b[it].z; a[it].w += b[it].w;
        ((float4*)out)[i] = a[it];
    }
}

extern "C" void kernel_launch(void* const* d_in, const int* in_sizes, int n_in,
                              void* d_out, int out_size, void* d_ws, size_t ws_size,
                              hipStream_t stream)
{
    const float* x        = (const float*)d_in[0];
    const float* gate_w   = (const float*)d_in[1];
    const float* gate_b   = (const float*)d_in[2];
    const float* expert_w = (const float*)d_in[3];
    const float* expert_b = (const float*)d_in[4];
    float* out = (float*)d_out;

    char* ws = (char*)d_ws;
    int*    eids      = (int*)(ws);                         // 32 KB
    float2* gatesv    = (float2*)(ws + (64 << 10));         // 64 KB
    int*    counts    = (int*)(ws + (132 << 10));           // 32 B
    int*    tok_list  = (int*)(ws + (136 << 10));           // 256 KB
    float*  gate_list = (float*)(ws + (136 << 10) + NE * N_TOK * 4); // 256 KB
    u16*    xbf       = (u16*)(ws + (1 << 20));             // 16 MB
    u16*    wbf       = xbf + (size_t)N_TOK * HDIM;         // 16 MB
    float*  part1     = (float*)(ws + (33u << 20));         // 32 MB

    prep_kernel<<<NCONV + NGATE, 256, 0, stream>>>(expert_w, wbf, x, gate_w, gate_b,
                                                   xbf, eids, gatesv, counts);
    compact_kernel<<<N_TOK / 256, 256, 0, stream>>>(eids, gatesv, tok_list, gate_list, counts);

    moe_gemm_kernel<<<GEMM_GRID, 512, 0, stream>>>(xbf, wbf, expert_b,
                                                   counts, tok_list, gate_list, out, part1);

    combine_kernel<<<N_TOK * HDIM / 16 / 256, 256, 0, stream>>>(out, part1);
}